// Round 6
// baseline (118.502 us; speedup 1.0000x reference)
//
#include <hip/hip_runtime.h>
#include <hip/hip_bf16.h>

#define WDIM 512
#define CHN  512
#define NB   32
#define SZ   64
#define MTOT 4096   // SZ*SZ

typedef __attribute__((ext_vector_type(4))) float f32x4;
typedef __attribute__((ext_vector_type(8))) short short8;
typedef __attribute__((ext_vector_type(4))) int   int4v;
typedef __attribute__((ext_vector_type(4))) float float4v;

#define SBAR() __builtin_amdgcn_sched_barrier(0)
// post-MFMA barrier: waits only LDS ops; global_load_lds DMA stays in flight
__device__ __forceinline__ void bar_lgkm() {
    SBAR();
    asm volatile("s_waitcnt lgkmcnt(0)" ::: "memory");
    __builtin_amdgcn_s_barrier();
    SBAR();
}
// post-features barrier: full drain (stage issued ~1200cy earlier -> free)
__device__ __forceinline__ void bar_full() {
    SBAR();
    asm volatile("s_waitcnt vmcnt(0) lgkmcnt(0)" ::: "memory");
    __builtin_amdgcn_s_barrier();
    SBAR();
}

// ---------------- setup: per-batch affine+norm, per-(n,c) params ----------------
__global__ __launch_bounds__(512) void setup_kernel(
    const float* __restrict__ w,
    const float* __restrict__ affine_w,
    const float* __restrict__ affine_b,
    const float* __restrict__ freqs,
    const float* __restrict__ phases,
    float* __restrict__ frx_o, float* __restrict__ fry_o,
    float* __restrict__ pha_o, float* __restrict__ amp_o)
{
    const int n = blockIdx.x;
    const int tid = threadIdx.x;
    __shared__ float red[8][4];
    __shared__ float par[4];

    float wv = w[n * WDIM + tid];
    float p0 = wv * affine_w[0 * WDIM + tid];
    float p1 = wv * affine_w[1 * WDIM + tid];
    float p2 = wv * affine_w[2 * WDIM + tid];
    float p3 = wv * affine_w[3 * WDIM + tid];
    #pragma unroll
    for (int off = 32; off >= 1; off >>= 1) {
        p0 += __shfl_down(p0, off);
        p1 += __shfl_down(p1, off);
        p2 += __shfl_down(p2, off);
        p3 += __shfl_down(p3, off);
    }
    const int wave = tid >> 6;
    if ((tid & 63) == 0) {
        red[wave][0] = p0; red[wave][1] = p1;
        red[wave][2] = p2; red[wave][3] = p3;
    }
    __syncthreads();
    if (tid == 0) {
        const float gain = 0.04419417382415922f; // 1/sqrt(512)
        float t[4];
        #pragma unroll
        for (int j = 0; j < 4; ++j) {
            float s = 0.0f;
            #pragma unroll
            for (int v = 0; v < 8; ++v) s += red[v][j];
            t[j] = s * gain + affine_b[j];
        }
        float inv = 1.0f / sqrtf(t[0] * t[0] + t[1] * t[1]);
        float c = t[0] * inv, s = t[1] * inv, tx = t[2] * inv, ty = t[3] * inv;
        par[0] = c;
        par[1] = s;
        par[2] = -c * tx + s * ty;
        par[3] = -s * tx - c * ty;
    }
    __syncthreads();
    const float c_ = par[0], s_ = par[1], tr0 = par[2], tr1 = par[3];
    const int ci = tid; // CH == 512 == blockDim
    float fx = freqs[ci * 2 + 0], fy = freqs[ci * 2 + 1];
    float frx = fx * c_ + fy * s_;
    float fry = -fx * s_ + fy * c_;
    float ph = phases[ci] + fx * tr0 + fy * tr1;
    float r = sqrtf(frx * frx + fry * fry);
    float amp = 1.0f - (r - 2.0f) * (1.0f / 30.0f); // (r-BW)/(SR/2-BW)
    amp = fminf(fmaxf(amp, 0.0f), 1.0f);
    frx_o[n * CHN + ci] = frx;
    fry_o[n * CHN + ci] = fry;
    pha_o[n * CHN + ci] = ph;
    amp_o[n * CHN + ci] = amp;
}

// ---------------- prep: A-tables, B-tables, weight->bf16 ----------------
// SA/CA[n][w][c] = amp*sin/cos(2pi*xs_w*frx);  SB/CB[n][h][c] = sin/cos(2pi*(ys_h*fry+ph))
__global__ __launch_bounds__(512) void prep_kernel(
    const float* __restrict__ frx, const float* __restrict__ fry,
    const float* __restrict__ pha, const float* __restrict__ amp,
    const float* __restrict__ wsrc,
    float* __restrict__ SA, float* __restrict__ CA,
    float* __restrict__ SB, float* __restrict__ CB,
    __hip_bfloat16* __restrict__ wbf)
{
    const int b = blockIdx.x;
    if (b < NB * 64) {
        const int n = b >> 6;
        const int w = b & 63;
        const int c = threadIdx.x;
        float fx = frx[n * CHN + c];
        float a  = amp[n * CHN + c];
        float fy = fry[n * CHN + c];
        float ph = pha[n * CHN + c];
        float xs = (float)(2 * w + 1) * (1.0f / 128.0f) - 0.5f; // == ys_w
        size_t idx = ((size_t)(n * 64 + w)) * CHN + c;
        SA[idx] = a * __builtin_amdgcn_sinf(xs * fx);
        CA[idx] = a * __builtin_amdgcn_cosf(xs * fx);
        float bb = xs * fy + ph;
        SB[idx] = __builtin_amdgcn_sinf(bb);
        CB[idx] = __builtin_amdgcn_cosf(bb);
    } else {
        int i = (b - NB * 64) * 512 + threadIdx.x;
        wbf[i] = __float2bfloat16(wsrc[i] * 0.04419417382415922f);
    }
}

// ---------------- fused features + GEMM ----------------
// 128(m) x 256(k) block tile, BK=64, 4 waves 1x4 (wave 128m x 64k, acc 4x8).
// Bs double-buffered (stage issued pre-MFMA, drained post-features);
// As single-buffered; raw barriers with counted waits; no LDS tables.
__global__ __launch_bounds__(256, 2) void fused_kernel(
    const float* __restrict__ SA, const float* __restrict__ CA,
    const float* __restrict__ SB, const float* __restrict__ CB,
    const __hip_bfloat16* __restrict__ wbf,
    float* __restrict__ out)
{
    __shared__ __align__(16) __hip_bfloat16 As[128 * 64];    // 16 KB
    __shared__ __align__(16) __hip_bfloat16 Bs[2][256 * 64]; // 64 KB

    const int tid = threadIdx.x;
    const int mb = blockIdx.x * 128;
    const int kb = blockIdx.y * 256;
    const int n  = blockIdx.z;
    const int h0 = mb >> 6;

    const int lane = tid & 63;
    const int wid  = tid >> 6;        // 0..3
    const int ln15 = lane & 15;
    const int hi4  = lane >> 4;
    const int wk   = wid * 64;

    const int cc0 = (tid & 7) * 8;
    const int rb  = tid >> 3;         // 0..31

    const float* saL = SA + ((size_t)(n * 64 + rb)) * CHN + cc0;
    const float* saH = saL + 32 * CHN;
    const float* caL = CA + ((size_t)(n * 64 + rb)) * CHN + cc0;
    const float* caH = caL + 32 * CHN;
    const float* sb0 = SB + ((size_t)(n * 64 + h0)) * CHN + cc0;
    const float* cb0 = CB + ((size_t)(n * 64 + h0)) * CHN + cc0;

    auto stageB = [&](int buf, int c0) {
        #pragma unroll
        for (int u = 0; u < 8; ++u) {
            int unit = u * 256 + tid;
            int row = unit >> 3;
            int cbyte = ((unit & 7) << 4) ^ ((row & 7) << 4);
            const __hip_bfloat16* src = wbf + (size_t)(kb + row) * CHN + c0 + (cbyte >> 1);
            char* ldsbase = (char*)Bs[buf] + (u * 256 + (wid << 6)) * 16; // wave-uniform
            __builtin_amdgcn_global_load_lds(
                (const __attribute__((address_space(1))) unsigned int*)src,
                (__attribute__((address_space(3))) unsigned int*)ldsbase, 16, 0, 0);
        }
    };

    // P prefetch registers (SA/CA slices) — issued pre-MFMA, consumed in features
    float4v Ps0, Ps1, Ps2, Ps3, Pq0, Pq1, Pq2, Pq3;
    auto loadP = [&](int c0) {
        Ps0 = *(const float4v*)(saL + c0); Ps1 = *(const float4v*)(saL + c0 + 4);
        Ps2 = *(const float4v*)(saH + c0); Ps3 = *(const float4v*)(saH + c0 + 4);
        Pq0 = *(const float4v*)(caL + c0); Pq1 = *(const float4v*)(caL + c0 + 4);
        Pq2 = *(const float4v*)(caH + c0); Pq3 = *(const float4v*)(caH + c0 + 4);
    };

    auto features = [&](int c0) {
        // Q: SB/CB slices for the block's two h rows (L2 hit, issued together)
        float4v B00 = *(const float4v*)(sb0 + c0),       B01 = *(const float4v*)(sb0 + c0 + 4);
        float4v B10 = *(const float4v*)(sb0 + CHN + c0), B11 = *(const float4v*)(sb0 + CHN + c0 + 4);
        float4v D00 = *(const float4v*)(cb0 + c0),       D01 = *(const float4v*)(cb0 + c0 + 4);
        float4v D10 = *(const float4v*)(cb0 + CHN + c0), D11 = *(const float4v*)(cb0 + CHN + c0 + 4);
        #pragma unroll
        for (int i = 0; i < 4; ++i) {
            int m = rb + i * 32;
            float4v A0 = (i & 1) ? Ps2 : Ps0, A1 = (i & 1) ? Ps3 : Ps1;
            float4v C0 = (i & 1) ? Pq2 : Pq0, C1 = (i & 1) ? Pq3 : Pq1;
            float4v Sb0 = (i >> 1) ? B10 : B00, Sb1 = (i >> 1) ? B11 : B01;
            float4v Cb0 = (i >> 1) ? D10 : D00, Cb1 = (i >> 1) ? D11 : D01;
            union { __hip_bfloat16 h[8]; int4v v; } t;
            #pragma unroll
            for (int j = 0; j < 4; ++j)
                t.h[j] = __float2bfloat16(A0[j] * Cb0[j] + C0[j] * Sb0[j]);
            #pragma unroll
            for (int j = 0; j < 4; ++j)
                t.h[4 + j] = __float2bfloat16(A1[j] * Cb1[j] + C1[j] * Sb1[j]);
            *(int4v*)((char*)As + m * 128 + ((cc0 * 2) ^ ((m & 7) << 4))) = t.v;
        }
    };

    f32x4 acc[4][8];
    #pragma unroll
    for (int a = 0; a < 4; ++a)
        #pragma unroll
        for (int b = 0; b < 8; ++b)
            acc[a][b] = (f32x4)0.0f;

    auto mfmaStep = [&](int buf) {
        #pragma unroll
        for (int kk = 0; kk < 2; ++kk) {
            short8 wf[4], ff[8];
            #pragma unroll
            for (int ki = 0; ki < 4; ++ki) {
                int row = wk + ki * 16 + ln15;
                wf[ki] = *(const short8*)((char*)Bs[buf] + row * 128 +
                          (((kk * 32 + hi4 * 8) * 2) ^ ((row & 7) << 4)));
            }
            #pragma unroll
            for (int mj = 0; mj < 8; ++mj) {
                int m = mj * 16 + ln15;
                ff[mj] = *(const short8*)((char*)As + m * 128 +
                          (((kk * 32 + hi4 * 8) * 2) ^ ((m & 7) << 4)));
            }
            #pragma unroll
            for (int ki = 0; ki < 4; ++ki)
                #pragma unroll
                for (int mj = 0; mj < 8; ++mj)
                    acc[ki][mj] = __builtin_amdgcn_mfma_f32_16x16x32_bf16(
                        wf[ki], ff[mj], acc[ki][mj], 0, 0, 0);
        }
    };

    // ---- prologue: stage tile0, build feature tile0 ----
    stageB(0, 0);
    loadP(0);
    features(0);   // P/Q waits force stage(0) retire too (FIFO) — fine, it landed
    bar_full();    // As visible, Bs[0] landed

    // ---- main loop: prepare tile kc+1 while computing tile kc ----
    #pragma unroll 1
    for (int kc = 0; kc < 7; ++kc) {
        const int c0n = (kc + 1) * 64;
        stageB((kc + 1) & 1, c0n);   // DMA into other buffer, in flight across MFMA
        loadP(c0n);                  // P regs for next features
        mfmaStep(kc & 1);
        bar_lgkm();                  // frag reads done (no vmcnt drain!)
        features(c0n);               // overwrite As for next tile
        bar_full();                  // As visible + Bs[next] drained (landed long ago)
    }
    mfmaStep(1);

    // ---- epilogue: out[n][k][hw], D col (ln15) = m -> coalesced ----
    #pragma unroll
    for (int ki = 0; ki < 4; ++ki) {
        #pragma unroll
        for (int mj = 0; mj < 8; ++mj) {
            int kg = kb + wk + ki * 16 + hi4 * 4;
            int mg = mb + mj * 16 + ln15;
            float* op = out + ((size_t)n * CHN + kg) * MTOT + mg;
            #pragma unroll
            for (int r = 0; r < 4; ++r)
                op[(size_t)r * MTOT] = acc[ki][mj][r];
        }
    }
}

extern "C" void kernel_launch(void* const* d_in, const int* in_sizes, int n_in,
                              void* d_out, int out_size, void* d_ws, size_t ws_size,
                              hipStream_t stream) {
    const float* w        = (const float*)d_in[0];
    const float* affine_w = (const float*)d_in[1];
    const float* affine_b = (const float*)d_in[2];
    const float* weight   = (const float*)d_in[3];
    const float* freqs    = (const float*)d_in[4];
    const float* phases   = (const float*)d_in[5];
    float* out = (float*)d_out;

    char* ws = (char*)d_ws;
    float* frx = (float*)(ws + 0);
    float* fry = (float*)(ws + 65536);
    float* pha = (float*)(ws + 131072);
    float* amp = (float*)(ws + 196608);
    __hip_bfloat16* wbf = (__hip_bfloat16*)(ws + 262144);        // 512 KB
    float* SA = (float*)(ws + (1u << 20));                       // 4 MB each
    float* CA = (float*)(ws + (1u << 20) + (4u << 20));
    float* SB = (float*)(ws + (1u << 20) + (8u << 20));
    float* CB = (float*)(ws + (1u << 20) + (12u << 20));

    setup_kernel<<<NB, 512, 0, stream>>>(w, affine_w, affine_b, freqs, phases,
                                         frx, fry, pha, amp);
    prep_kernel<<<NB * 64 + (CHN * CHN) / 512, 512, 0, stream>>>(
        frx, fry, pha, amp, weight, SA, CA, SB, CB, wbf);

    dim3 grid(MTOT / 128, CHN / 256, NB);
    fused_kernel<<<grid, 256, 0, stream>>>(SA, CA, SB, CB, wbf, out);
}